// Round 7
// baseline (53.521 us; speedup 1.0000x reference)
//
#include <hip/hip_runtime.h>
#include <hip/hip_fp16.h>

#define BB 16
#define DD 512
#define NN 4096
#define KK 32
#define TNS 32          // n per subtile
#define SUBT 4          // subtiles per block (block owns 128 n)
#define NGRP 32         // n-groups (blocks) per batch
#define NBLK (BB*NGRP)  // 512 blocks
#define ROWX 40         // xbuf row stride (bf16 elems), 80 B
#define ROWA 40         // a_t row stride

// LDS byte offsets (total 77824 <= 80 KB -> 2 blocks/CU)
#define OFF_XBUF 0              // bf16 [512][40] = 40960
#define OFF_CLDS 40960          // bf16 c swizzled [32][512] = 32768
#define OFF_AT   73728          // bf16 [32][40] = 2560
#define OFF_X2P  76288          // f32 [8][32] = 1024
#define OFF_S2   77312          // f32 [32]
#define OFF_C2   77440          // f32 [32]
#define OFF_ASUM 77568          // f32 [2][32]
#define LDS_TOTAL 77824

typedef unsigned short u16;
typedef __attribute__((ext_vector_type(8))) short short8v;
typedef __attribute__((ext_vector_type(4))) float f32x4;

#define SYNCL() asm volatile("s_waitcnt lgkmcnt(0)\n\ts_barrier" ::: "memory")

__device__ __forceinline__ unsigned f2bf(float f) {
    union { float f; unsigned u; } v; v.f = f;
    unsigned r = v.u + 0x7fff + ((v.u >> 16) & 1);   // RNE
    return r >> 16;
}

// ---------------- K0: prep codewords (bf16 copy, c2, s2); 1 wave per k ----
__global__ void k0_prep(const float* __restrict__ cw, const float* __restrict__ scale,
                        u16* __restrict__ c_bf, float* __restrict__ c2,
                        float* __restrict__ s2) {
    const int k = blockIdx.x;       // 32 blocks
    const int l = threadIdx.x;      // 64 threads
    const float* row = cw + k * DD;
    float s = 0.f;
#pragma unroll
    for (int j = 0; j < 8; ++j) {
        float v = row[j * 64 + l];
        s += v * v;
        c_bf[k * DD + j * 64 + l] = (u16)f2bf(v);
    }
#pragma unroll
    for (int off = 32; off; off >>= 1) s += __shfl_xor(s, off);
    if (l == 0) { c2[k] = s; float sc = scale[k]; s2[k] = sc * sc; }
}

// ---------------- K1: fused, register-staged, 2 blocks/CU ----------------
template <typename PART>
__global__ __launch_bounds__(512, 4)
void k1_fused(const float* __restrict__ x, const u16* __restrict__ c_bf,
              const float* __restrict__ c2g, const float* __restrict__ s2g,
              float* __restrict__ ws_asum, PART* __restrict__ ws_e) {
    extern __shared__ char smem[];
    u16*   xbuf    = (u16*)(smem + OFF_XBUF);
    u16*   c_lds   = (u16*)(smem + OFF_CLDS);
    u16*   a_t     = (u16*)(smem + OFF_AT);
    float* x2_part = (float*)(smem + OFF_X2P);
    float* s2_l    = (float*)(smem + OFF_S2);
    float* c2_l    = (float*)(smem + OFF_C2);
    float* asum_p  = (float*)(smem + OFF_ASUM);

    const int t = threadIdx.x;
    const int l = t & 63, w = t >> 6;        // lane, wave (8 waves)
    const int g = l >> 4, li = l & 15;       // 16-lane group, group-lane
    const int blk = blockIdx.x;
    const int b = blk >> 5, grp = blk & 31;
    const int n0 = grp * 128;
    const float* xrow = x + (size_t)b * DD * NN + (size_t)t * NN + n0; // row d = t

    // ---- prologue: issue subtile-0 loads first (latency overlaps c staging)
    float4 va[8];
#pragma unroll
    for (int j = 0; j < 8; ++j) va[j] = *(const float4*)(xrow + 4 * j);

    // ---- c -> LDS (chunk-swizzled rows), s2/c2 -> LDS ----
    {
        const int k = t >> 4, seg = t & 15;
#pragma unroll
        for (int j = 0; j < 4; ++j) {
            const int dch = seg * 4 + j;                 // 16B chunk idx 0..63
            short8v v = *(const short8v*)(c_bf + k * DD + dch * 8);
            *(short8v*)(c_lds + k * DD + ((dch ^ (k & 7)) << 3)) = v;
        }
        if (t < KK) { s2_l[t] = s2g[t]; c2_l[t] = c2g[t]; }
    }
    // c_lds/s2/c2 first read is after the convert SYNCL below — covered.

    f32x4 accB[8];
#pragma unroll
    for (int dt = 0; dt < 8; ++dt) accB[dt] = (f32x4){0.f, 0.f, 0.f, 0.f};
    float asum_acc[8] = {0.f, 0.f, 0.f, 0.f, 0.f, 0.f, 0.f, 0.f};

#pragma unroll
    for (int s = 0; s < SUBT; ++s) {
        // ---- convert va -> xbuf row t (4 swizzled b128 chunk writes) ----
#pragma unroll
        for (int c = 0; c < 4; ++c) {
            uint4 pk;
            asm("v_cvt_pk_bf16_f32 %0, %1, %2" : "=v"(pk.x) : "v"(va[2*c].x),   "v"(va[2*c].y));
            asm("v_cvt_pk_bf16_f32 %0, %1, %2" : "=v"(pk.y) : "v"(va[2*c].z),   "v"(va[2*c].w));
            asm("v_cvt_pk_bf16_f32 %0, %1, %2" : "=v"(pk.z) : "v"(va[2*c+1].x), "v"(va[2*c+1].y));
            asm("v_cvt_pk_bf16_f32 %0, %1, %2" : "=v"(pk.w) : "v"(va[2*c+1].z), "v"(va[2*c+1].w));
            *(uint4*)((char*)smem + OFF_XBUF + t * 80 + ((c ^ (t & 3)) << 4)) = pk;
        }
        SYNCL();   // xbuf(s) visible; also gates c_lds (s=0) / phase-B(s-1) reads

        // ---- issue next subtile's loads; they fly across A/SM/B ----
        if (s < SUBT - 1) {
#pragma unroll
            for (int j = 0; j < 8; ++j)
                va[j] = *(const float4*)(xrow + (s + 1) * TNS + 4 * j);
        }

        // ---- phase A (waves 0-1): logits = c . x ; waves 4-7: x2 from xbuf
        f32x4 accA0 = {0.f, 0.f, 0.f, 0.f}, accA1 = {0.f, 0.f, 0.f, 0.f};
        if (w < 2) {
            const int nloc = w * 16 + li;
            const int nc = nloc >> 3, nr = nloc & 7;
            for (int ch = 0; ch < 16; ++ch) {
                const int dbase = ch * 32 + g * 8;
                short8v bf;
#pragma unroll
                for (int j = 0; j < 8; ++j) {
                    const int d = dbase + j;
                    bf[j] = (short)xbuf[d * ROWX + ((nc ^ (d & 3)) << 3) + nr];
                }
                const int csw = ((ch * 4 + g) ^ (li & 7)) << 3;
                short8v a0 = *(const short8v*)(c_lds + li * DD + csw);
                short8v a1 = *(const short8v*)(c_lds + (16 + li) * DD + csw);
                accA0 = __builtin_amdgcn_mfma_f32_16x16x32_bf16(a0, bf, accA0, 0, 0, 0);
                accA1 = __builtin_amdgcn_mfma_f32_16x16x32_bf16(a1, bf, accA1, 0, 0, 0);
            }
        } else if (w >= 4) {
            const int n = l & 31, dgrp = (w - 4) * 2 + (l >> 5);
            const int nch = n >> 3, nr = n & 7;
            float sx = 0.f;
#pragma unroll
            for (int j = 0; j < 64; ++j) {
                const int d = dgrp * 64 + j;
                unsigned u = xbuf[d * ROWX + ((nch ^ (d & 3)) << 3) + nr];
                union { unsigned u; float f; } cv; cv.u = u << 16;
                sx += cv.f * cv.f;
            }
            x2_part[dgrp * 32 + n] = sx;
        }
        SYNCL();   // x2_part ready

        // ---- softmax (waves 0-1); a_t write; asum accumulate ----
        if (w < 2) {
            const int nloc = w * 16 + li;
            float x2v = 0.f;
#pragma unroll
            for (int p = 0; p < 8; ++p) x2v += x2_part[p * 32 + nloc];
            float sl[8];
            float mx = -3.4e38f;
#pragma unroll
            for (int r = 0; r < 4; ++r) {
                float v0 = s2_l[4 * g + r]      * (x2v - 2.f * accA0[r] + c2_l[4 * g + r]);
                float v1 = s2_l[16 + 4 * g + r] * (x2v - 2.f * accA1[r] + c2_l[16 + 4 * g + r]);
                sl[r] = v0; sl[4 + r] = v1;
                mx = fmaxf(mx, fmaxf(v0, v1));
            }
            mx = fmaxf(mx, __shfl_xor(mx, 16));
            mx = fmaxf(mx, __shfl_xor(mx, 32));
            float sum = 0.f;
#pragma unroll
            for (int i = 0; i < 8; ++i) { sl[i] = __expf(sl[i] - mx); sum += sl[i]; }
            sum += __shfl_xor(sum, 16);
            sum += __shfl_xor(sum, 32);
            const float inv = 1.f / sum;
#pragma unroll
            for (int i = 0; i < 8; ++i) {
                float a = sl[i] * inv;
                int k = (i < 4) ? (4 * g + i) : (16 + 4 * g + (i - 4));
                a_t[k * ROWA + nloc] = (u16)f2bf(a);
                float ssum = a;
                ssum += __shfl_xor(ssum, 1); ssum += __shfl_xor(ssum, 2);
                ssum += __shfl_xor(ssum, 4); ssum += __shfl_xor(ssum, 8);
                asum_acc[i] += ssum;    // valid on li==0
            }
        }
        SYNCL();   // a_t ready

        // ---- phase B (all 8 waves): e[k-tile][128 d per wave] += a . x^T ----
        {
            const int kt = w >> 2, dblk = w & 3;
            short8v af = *(const short8v*)(a_t + (kt * 16 + li) * ROWA + g * 8);
#pragma unroll
            for (int dt = 0; dt < 8; ++dt) {
                const int d = dblk * 128 + dt * 16 + li;
                short8v xf = *(const short8v*)(xbuf + d * ROWX + ((g ^ (d & 3)) << 3));
                accB[dt] = __builtin_amdgcn_mfma_f32_16x16x32_bf16(af, xf, accB[dt], 0, 0, 0);
            }
        }
        SYNCL();   // xbuf free for next convert
    }

    // ---- asum -> ws ----
    if (w < 2 && li == 0) {
#pragma unroll
        for (int i = 0; i < 8; ++i) {
            int k = (i < 4) ? (4 * g + i) : (16 + 4 * g + (i - 4));
            asum_p[w * KK + k] = asum_acc[i];
        }
    }
    __syncthreads();
    if (t < KK) ws_asum[(size_t)blk * KK + t] = asum_p[t] + asum_p[KK + t];

    // ---- e partials -> ws (once per block) ----
    {
        const int kt = w >> 2, dblk = w & 3;
        const size_t ebase = (size_t)blk * KK * DD;
#pragma unroll
        for (int dt = 0; dt < 8; ++dt)
#pragma unroll
            for (int r = 0; r < 4; ++r) {
                int k = kt * 16 + 4 * g + r;
                int d = dblk * 128 + dt * 16 + li;
                ws_e[ebase + (size_t)k * DD + d] = (PART)(accB[dt][r]);
            }
    }
}

// ---------------- K2: reduce 32 partials, subtract asum*c ----------------
__global__ void k2_reduce_h(const __half2* __restrict__ ws_e, const float* __restrict__ ws_asum,
                            const float* __restrict__ cw, float* __restrict__ out) {
    int tid = blockIdx.x * blockDim.x + threadIdx.x;   // 131072
    int d2 = tid & 255;
    int k = (tid >> 8) & (KK - 1);
    int b = tid >> 13;
    const __half2* pe = ws_e + ((size_t)(b * NGRP) * KK + k) * 256 + d2;
    const float* pa = ws_asum + b * NGRP * KK + k;
    float s0 = 0.f, s1 = 0.f, as = 0.f;
#pragma unroll
    for (int tl = 0; tl < NGRP; ++tl) {
        float2 f = __half22float2(pe[(size_t)tl * KK * 256]);
        s0 += f.x; s1 += f.y;
        as += pa[tl * KK];
    }
    int d = d2 * 2;
    float c0 = cw[k * DD + d], c1 = cw[k * DD + d + 1];
    float2 o; o.x = s0 - as * c0; o.y = s1 - as * c1;
    *(float2*)(out + ((size_t)(b * KK + k) * DD + d)) = o;
}

__global__ void k2_reduce_f(const float* __restrict__ ws_e, const float* __restrict__ ws_asum,
                            const float* __restrict__ cw, float* __restrict__ out) {
    int tid = blockIdx.x * blockDim.x + threadIdx.x;   // 262144
    int d = tid & (DD - 1);
    int k = (tid >> 9) & (KK - 1);
    int b = tid >> 14;
    float s = 0.f, as = 0.f;
#pragma unroll
    for (int tl = 0; tl < NGRP; ++tl) {
        int blk = b * NGRP + tl;
        s += ws_e[((size_t)blk * KK + k) * DD + d];
        as += ws_asum[(size_t)blk * KK + k];
    }
    out[tid] = s - as * cw[k * DD + d];
}

extern "C" void kernel_launch(void* const* d_in, const int* in_sizes, int n_in,
                              void* d_out, int out_size, void* d_ws, size_t ws_size,
                              hipStream_t stream) {
    const float* x = (const float*)d_in[0];
    const float* cw = (const float*)d_in[1];
    const float* scale = (const float*)d_in[2];
    float* out = (float*)d_out;

    char* ws = (char*)d_ws;
    u16*   c_bf    = (u16*)ws;                  // 32768 B
    float* c2      = (float*)(ws + 32768);
    float* s2      = (float*)(ws + 32896);
    float* ws_asum = (float*)(ws + 33024);      // 512*32*4 = 65536 B
    char*  e_ptr   = ws + 98560;

    const size_t need_h = 98560 + (size_t)NBLK * KK * DD * sizeof(__half);

    k0_prep<<<KK, 64, 0, stream>>>(cw, scale, c_bf, c2, s2);
    if (ws_size >= need_h) {
        k1_fused<__half><<<NBLK, 512, LDS_TOTAL, stream>>>(x, c_bf, c2, s2, ws_asum, (__half*)e_ptr);
        k2_reduce_h<<<(BB * KK * 256) / 256, 256, 0, stream>>>((const __half2*)e_ptr, ws_asum, cw, out);
    } else {
        k1_fused<float><<<NBLK, 512, LDS_TOTAL, stream>>>(x, c_bf, c2, s2, ws_asum, (float*)e_ptr);
        k2_reduce_f<<<(BB * KK * DD) / 256, 256, 0, stream>>>((const float*)e_ptr, ws_asum, cw, out);
    }
}

// Round 8
// 43.947 us; speedup vs baseline: 1.2179x; 1.2179x over previous
//
#include <hip/hip_runtime.h>
#include <hip/hip_fp16.h>

#define BB 16
#define DD 512
#define NN 4096
#define KK 32
#define TNS 32          // n per subtile
#define SUBT 4          // subtiles per block (block owns 128 n)
#define NGRP 32         // n-groups (blocks) per batch
#define NBLK (BB*NGRP)  // 512 blocks
#define ROWX 40         // xbuf row stride (bf16 elems), 80 B
#define ROWA 40         // a_t row stride

// LDS byte offsets (total 77824 -> 2 blocks/CU)
#define OFF_XBUF 0              // bf16 [512][40] = 40960
#define OFF_CLDS 40960          // bf16 c swizzled [32][512] = 32768
#define OFF_AT   73728          // bf16 [32][40] = 2560
#define OFF_X2P  76288          // f32 [8][32] = 1024
#define OFF_S2   77312          // f32 [32]
#define OFF_C2   77440          // f32 [32]
#define OFF_ASUM 77568          // f32 [2][32]
#define LDS_TOTAL 77824

typedef unsigned short u16;
typedef __attribute__((ext_vector_type(8))) short short8v;
typedef __attribute__((ext_vector_type(4))) float f32x4;

#define SYNCL() asm volatile("s_waitcnt lgkmcnt(0)\n\ts_barrier" ::: "memory")

__device__ __forceinline__ unsigned f2bf(float f) {
    union { float f; unsigned u; } v; v.f = f;
    unsigned r = v.u + 0x7fff + ((v.u >> 16) & 1);   // RNE
    return r >> 16;
}

// ---------------- K0: prep codewords (bf16 copy, c2, s2); 1 wave per k ----
__global__ void k0_prep(const float* __restrict__ cw, const float* __restrict__ scale,
                        u16* __restrict__ c_bf, float* __restrict__ c2,
                        float* __restrict__ s2) {
    const int k = blockIdx.x;       // 32 blocks
    const int l = threadIdx.x;      // 64 threads
    const float* row = cw + k * DD;
    float s = 0.f;
#pragma unroll
    for (int j = 0; j < 8; ++j) {
        float v = row[j * 64 + l];
        s += v * v;
        c_bf[k * DD + j * 64 + l] = (u16)f2bf(v);
    }
#pragma unroll
    for (int off = 32; off; off >>= 1) s += __shfl_xor(s, off);
    if (l == 0) { c2[k] = s; float sc = scale[k]; s2[k] = sc * sc; }
}

// ---------------- K1: fused, coalesced register staging, 2 blocks/CU -----
template <typename PART>
__global__ __launch_bounds__(512, 4)
void k1_fused(const float* __restrict__ x, const u16* __restrict__ c_bf,
              const float* __restrict__ c2g, const float* __restrict__ s2g,
              float* __restrict__ ws_asum, PART* __restrict__ ws_e) {
    extern __shared__ char smem[];
    u16*   xbuf    = (u16*)(smem + OFF_XBUF);
    u16*   c_lds   = (u16*)(smem + OFF_CLDS);
    u16*   a_t     = (u16*)(smem + OFF_AT);
    float* x2_part = (float*)(smem + OFF_X2P);
    float* s2_l    = (float*)(smem + OFF_S2);
    float* c2_l    = (float*)(smem + OFF_C2);
    float* asum_p  = (float*)(smem + OFF_ASUM);

    const int t = threadIdx.x;
    const int l = t & 63, w = t >> 6;        // lane, wave (8 waves)
    const int g = l >> 4, li = l & 15;       // 16-lane group, group-lane
    const int blk = blockIdx.x;
    const int b = blk >> 5, grp = blk & 31;
    const int n0 = grp * 128;
    const float* xg = x + (size_t)b * DD * NN + n0;

    // staging geometry: wave w owns rows [64w, 64w+64)
    const int lr = l >> 3;                   // row-subgroup 0..7
    const int lc = l & 7;                    // 16B col-group within 32-n subtile
    const int cp = lc >> 1, lo = lc & 1;     // chunk-pair + half
    const float* xrow = xg + (size_t)(w * 64 + lr) * NN + lc * 4;
    // per-thread constant swizzled write offset: row r = w*64 + 8j + lr, r&3 == lr&3
    const int wswz = ((cp ^ (lr & 3)) << 4) | (lo << 3);

    // ---- prologue: issue subtile-0 loads first ----
    float4 va[8];
#pragma unroll
    for (int j = 0; j < 8; ++j) va[j] = *(const float4*)(xrow + (size_t)(j * 8) * NN);

    // ---- c -> LDS (chunk-swizzled rows), s2/c2 -> LDS ----
    {
        const int k = t >> 4, seg = t & 15;
#pragma unroll
        for (int j = 0; j < 4; ++j) {
            const int dch = seg * 4 + j;                 // 16B chunk idx 0..63
            short8v v = *(const short8v*)(c_bf + k * DD + dch * 8);
            *(short8v*)(c_lds + k * DD + ((dch ^ (k & 7)) << 3)) = v;
        }
        if (t < KK) { s2_l[t] = s2g[t]; c2_l[t] = c2g[t]; }
    }

    f32x4 accB[8];
#pragma unroll
    for (int dt = 0; dt < 8; ++dt) accB[dt] = (f32x4){0.f, 0.f, 0.f, 0.f};
    float asum_acc[8] = {0.f, 0.f, 0.f, 0.f, 0.f, 0.f, 0.f, 0.f};

#pragma unroll
    for (int s = 0; s < SUBT; ++s) {
        // ---- convert va -> xbuf (swizzled b64 writes) + x2 partials ----
        {
            float p0 = 0, p1 = 0, p2 = 0, p3 = 0;
#pragma unroll
            for (int j = 0; j < 8; ++j) {
                uint2 pk;
                asm("v_cvt_pk_bf16_f32 %0, %1, %2" : "=v"(pk.x) : "v"(va[j].x), "v"(va[j].y));
                asm("v_cvt_pk_bf16_f32 %0, %1, %2" : "=v"(pk.y) : "v"(va[j].z), "v"(va[j].w));
                const int r = w * 64 + j * 8 + lr;
                *(uint2*)(smem + OFF_XBUF + r * 80 + wswz) = pk;
                p0 += va[j].x * va[j].x; p1 += va[j].y * va[j].y;
                p2 += va[j].z * va[j].z; p3 += va[j].w * va[j].w;
            }
            // reduce across the wave's 8 row-subgroups (lanes sharing lc)
            p0 += __shfl_xor(p0, 8); p0 += __shfl_xor(p0, 16); p0 += __shfl_xor(p0, 32);
            p1 += __shfl_xor(p1, 8); p1 += __shfl_xor(p1, 16); p1 += __shfl_xor(p1, 32);
            p2 += __shfl_xor(p2, 8); p2 += __shfl_xor(p2, 16); p2 += __shfl_xor(p2, 32);
            p3 += __shfl_xor(p3, 8); p3 += __shfl_xor(p3, 16); p3 += __shfl_xor(p3, 32);
            if (lr == 0) {
                float4 p4 = {p0, p1, p2, p3};
                *(float4*)((char*)smem + OFF_X2P + w * 128 + lc * 16) = p4;
            }
        }
        SYNCL();   // 1: xbuf + x2_part visible (also gates c_lds at s=0)

        // ---- issue next subtile's loads; they fly across A/SM/B ----
        if (s < SUBT - 1) {
#pragma unroll
            for (int j = 0; j < 8; ++j)
                va[j] = *(const float4*)(xrow + (size_t)(j * 8) * NN + (s + 1) * TNS);
        }

        // ---- phase A + softmax fused (waves 0-1) ----
        if (w < 2) {
            f32x4 accA0 = {0.f, 0.f, 0.f, 0.f}, accA1 = {0.f, 0.f, 0.f, 0.f};
            const int nloc = w * 16 + li;
            const int nc = nloc >> 3, nr = nloc & 7;
            for (int ch = 0; ch < 16; ++ch) {
                const int dbase = ch * 32 + g * 8;
                short8v bf;
#pragma unroll
                for (int j = 0; j < 8; ++j) {
                    const int d = dbase + j;
                    bf[j] = (short)xbuf[d * ROWX + ((nc ^ (d & 3)) << 3) + nr];
                }
                const int csw = ((ch * 4 + g) ^ (li & 7)) << 3;
                short8v a0 = *(const short8v*)(c_lds + li * DD + csw);
                short8v a1 = *(const short8v*)(c_lds + (16 + li) * DD + csw);
                accA0 = __builtin_amdgcn_mfma_f32_16x16x32_bf16(a0, bf, accA0, 0, 0, 0);
                accA1 = __builtin_amdgcn_mfma_f32_16x16x32_bf16(a1, bf, accA1, 0, 0, 0);
            }
            // softmax over k for column nloc
            float x2v = 0.f;
#pragma unroll
            for (int p = 0; p < 8; ++p) x2v += x2_part[p * 32 + nloc];
            float sl[8];
            float mx = -3.4e38f;
#pragma unroll
            for (int r = 0; r < 4; ++r) {
                float v0 = s2_l[4 * g + r]      * (x2v - 2.f * accA0[r] + c2_l[4 * g + r]);
                float v1 = s2_l[16 + 4 * g + r] * (x2v - 2.f * accA1[r] + c2_l[16 + 4 * g + r]);
                sl[r] = v0; sl[4 + r] = v1;
                mx = fmaxf(mx, fmaxf(v0, v1));
            }
            mx = fmaxf(mx, __shfl_xor(mx, 16));
            mx = fmaxf(mx, __shfl_xor(mx, 32));
            float sum = 0.f;
#pragma unroll
            for (int i = 0; i < 8; ++i) { sl[i] = __expf(sl[i] - mx); sum += sl[i]; }
            sum += __shfl_xor(sum, 16);
            sum += __shfl_xor(sum, 32);
            const float inv = 1.f / sum;
#pragma unroll
            for (int i = 0; i < 8; ++i) {
                float a = sl[i] * inv;
                int k = (i < 4) ? (4 * g + i) : (16 + 4 * g + (i - 4));
                a_t[k * ROWA + nloc] = (u16)f2bf(a);
                float ssum = a;
                ssum += __shfl_xor(ssum, 1); ssum += __shfl_xor(ssum, 2);
                ssum += __shfl_xor(ssum, 4); ssum += __shfl_xor(ssum, 8);
                asum_acc[i] += ssum;    // valid on li==0
            }
        }
        SYNCL();   // 2: a_t ready

        // ---- phase B (all 8 waves): e[k-tile][128 d per wave] += a . x^T ----
        {
            const int kt = w >> 2, dblk = w & 3;
            short8v af = *(const short8v*)(a_t + (kt * 16 + li) * ROWA + g * 8);
#pragma unroll
            for (int dt = 0; dt < 8; ++dt) {
                const int d = dblk * 128 + dt * 16 + li;
                short8v xf = *(const short8v*)(xbuf + d * ROWX + ((g ^ (d & 3)) << 3));
                accB[dt] = __builtin_amdgcn_mfma_f32_16x16x32_bf16(af, xf, accB[dt], 0, 0, 0);
            }
        }
        SYNCL();   // 3: xbuf free for next convert
    }

    // ---- asum -> ws ----
    if (w < 2 && li == 0) {
#pragma unroll
        for (int i = 0; i < 8; ++i) {
            int k = (i < 4) ? (4 * g + i) : (16 + 4 * g + (i - 4));
            asum_p[w * KK + k] = asum_acc[i];
        }
    }
    __syncthreads();
    if (t < KK) ws_asum[(size_t)blk * KK + t] = asum_p[t] + asum_p[KK + t];

    // ---- e partials -> ws (once per block) ----
    {
        const int kt = w >> 2, dblk = w & 3;
        const size_t ebase = (size_t)blk * KK * DD;
#pragma unroll
        for (int dt = 0; dt < 8; ++dt)
#pragma unroll
            for (int r = 0; r < 4; ++r) {
                int k = kt * 16 + 4 * g + r;
                int d = dblk * 128 + dt * 16 + li;
                ws_e[ebase + (size_t)k * DD + d] = (PART)(accB[dt][r]);
            }
    }
}

// ---------------- K2: reduce 32 partials, subtract asum*c ----------------
__global__ void k2_reduce_h(const __half2* __restrict__ ws_e, const float* __restrict__ ws_asum,
                            const float* __restrict__ cw, float* __restrict__ out) {
    int tid = blockIdx.x * blockDim.x + threadIdx.x;   // 131072
    int d2 = tid & 255;
    int k = (tid >> 8) & (KK - 1);
    int b = tid >> 13;
    const __half2* pe = ws_e + ((size_t)(b * NGRP) * KK + k) * 256 + d2;
    const float* pa = ws_asum + b * NGRP * KK + k;
    float s0 = 0.f, s1 = 0.f, as = 0.f;
#pragma unroll
    for (int tl = 0; tl < NGRP; ++tl) {
        float2 f = __half22float2(pe[(size_t)tl * KK * 256]);
        s0 += f.x; s1 += f.y;
        as += pa[tl * KK];
    }
    int d = d2 * 2;
    float c0 = cw[k * DD + d], c1 = cw[k * DD + d + 1];
    float2 o; o.x = s0 - as * c0; o.y = s1 - as * c1;
    *(float2*)(out + ((size_t)(b * KK + k) * DD + d)) = o;
}

__global__ void k2_reduce_f(const float* __restrict__ ws_e, const float* __restrict__ ws_asum,
                            const float* __restrict__ cw, float* __restrict__ out) {
    int tid = blockIdx.x * blockDim.x + threadIdx.x;   // 262144
    int d = tid & (DD - 1);
    int k = (tid >> 9) & (KK - 1);
    int b = tid >> 14;
    float s = 0.f, as = 0.f;
#pragma unroll
    for (int tl = 0; tl < NGRP; ++tl) {
        int blk = b * NGRP + tl;
        s += ws_e[((size_t)blk * KK + k) * DD + d];
        as += ws_asum[(size_t)blk * KK + k];
    }
    out[tid] = s - as * cw[k * DD + d];
}

extern "C" void kernel_launch(void* const* d_in, const int* in_sizes, int n_in,
                              void* d_out, int out_size, void* d_ws, size_t ws_size,
                              hipStream_t stream) {
    const float* x = (const float*)d_in[0];
    const float* cw = (const float*)d_in[1];
    const float* scale = (const float*)d_in[2];
    float* out = (float*)d_out;

    char* ws = (char*)d_ws;
    u16*   c_bf    = (u16*)ws;                  // 32768 B
    float* c2      = (float*)(ws + 32768);
    float* s2      = (float*)(ws + 32896);
    float* ws_asum = (float*)(ws + 33024);      // 512*32*4 = 65536 B
    char*  e_ptr   = ws + 98560;

    const size_t need_h = 98560 + (size_t)NBLK * KK * DD * sizeof(__half);

    k0_prep<<<KK, 64, 0, stream>>>(cw, scale, c_bf, c2, s2);
    if (ws_size >= need_h) {
        k1_fused<__half><<<NBLK, 512, LDS_TOTAL, stream>>>(x, c_bf, c2, s2, ws_asum, (__half*)e_ptr);
        k2_reduce_h<<<(BB * KK * 256) / 256, 256, 0, stream>>>((const __half2*)e_ptr, ws_asum, cw, out);
    } else {
        k1_fused<float><<<NBLK, 512, LDS_TOTAL, stream>>>(x, c_bf, c2, s2, ws_asum, (float*)e_ptr);
        k2_reduce_f<<<(BB * KK * DD) / 256, 256, 0, stream>>>((const float*)e_ptr, ws_asum, cw, out);
    }
}

// Round 9
// 38.444 us; speedup vs baseline: 1.3922x; 1.1431x over previous
//
#include <hip/hip_runtime.h>
#include <hip/hip_fp16.h>

#define BB 16
#define DD 512
#define NN 4096
#define KK 32
#define TNS 32          // n per subtile
#define SUBT 4          // subtiles per block (block owns 128 n)
#define NGRP 32         // n-groups (blocks) per batch
#define NBLK (BB*NGRP)  // 512 blocks
#define ROWX 40         // xbuf row stride (bf16 elems), 80 B
#define ROWA 40         // a_t row stride

// LDS byte offsets (total 77824 -> 2 blocks/CU)
#define OFF_XBUF 0              // bf16 [512][40] = 40960
#define OFF_CLDS 40960          // bf16 c swizzled [32][512] = 32768
#define OFF_AT   73728          // bf16 [32][40] = 2560
#define OFF_X2P  76288          // f32 [8][32] = 1024
#define OFF_S2   77312          // f32 [32]
#define OFF_C2   77440          // f32 [32]
#define OFF_ASUM 77568          // f32 [2][32]
#define LDS_TOTAL 77824

typedef unsigned short u16;
typedef __attribute__((ext_vector_type(8))) short short8v;
typedef __attribute__((ext_vector_type(4))) float f32x4;

#define SYNCL() asm volatile("s_waitcnt lgkmcnt(0)\n\ts_barrier" ::: "memory")

__device__ __forceinline__ unsigned f2bf(float f) {
    union { float f; unsigned u; } v; v.f = f;
    unsigned r = v.u + 0x7fff + ((v.u >> 16) & 1);   // RNE
    return r >> 16;
}

// ---------------- K1: fused, staggered staging, folded c-prep ------------
template <typename PART>
__global__ __launch_bounds__(512, 4)
void k1_fused(const float* __restrict__ x, const float* __restrict__ cw,
              const float* __restrict__ scale,
              float* __restrict__ ws_asum, PART* __restrict__ ws_e) {
    extern __shared__ char smem[];
    u16*   xbuf    = (u16*)(smem + OFF_XBUF);
    u16*   c_lds   = (u16*)(smem + OFF_CLDS);
    u16*   a_t     = (u16*)(smem + OFF_AT);
    float* x2_part = (float*)(smem + OFF_X2P);
    float* s2_l    = (float*)(smem + OFF_S2);
    float* c2_l    = (float*)(smem + OFF_C2);
    float* asum_p  = (float*)(smem + OFF_ASUM);

    const int t = threadIdx.x;
    const int l = t & 63, w = t >> 6;        // lane, wave (8 waves)
    const int g = l >> 4, li = l & 15;       // 16-lane group, group-lane
    const int blk = blockIdx.x;
    const int b = blk >> 5, grp = blk & 31;
    const int n0 = grp * 128;
    const float* xg = x + (size_t)b * DD * NN + n0;

    // staging geometry: wave w owns rows [64w, 64w+64)
    const int lr = l >> 3;                   // row-subgroup 0..7
    const int lc = l & 7;                    // 16B col-group within 32-n subtile
    const int cp = lc >> 1, lo = lc & 1;     // chunk-pair + half
    const float* xrow = xg + (size_t)(w * 64 + lr) * NN + lc * 4;
    const int wswz = ((cp ^ (lr & 3)) << 4) | (lo << 3);

    // ---- prologue: c-row loads first (so their waits don't drain va) ----
    const int ck = t >> 4, cseg = t & 15;    // 16 threads per k-row
    float4 cv[8];
    {
        const float* crow = cw + ck * DD + cseg * 32;
#pragma unroll
        for (int j = 0; j < 8; ++j) cv[j] = *(const float4*)(crow + 4 * j);
    }

    // ---- issue subtile-0 x loads (two halves) ----
    float4 vaA[4], vaB[4];
#pragma unroll
    for (int j = 0; j < 4; ++j) vaA[j] = *(const float4*)(xrow + (size_t)(j * 8) * NN);
#pragma unroll
    for (int j = 0; j < 4; ++j) vaB[j] = *(const float4*)(xrow + (size_t)((j + 4) * 8) * NN);

    // ---- stage c -> c_lds (chunk-swizzled) + c2 via 16-lane reduce ----
    {
        float c2p = 0.f;
#pragma unroll
        for (int j = 0; j < 8; ++j)
            c2p += cv[j].x * cv[j].x + cv[j].y * cv[j].y
                 + cv[j].z * cv[j].z + cv[j].w * cv[j].w;
#pragma unroll
        for (int j = 0; j < 4; ++j) {
            uint4 pk;
            asm("v_cvt_pk_bf16_f32 %0, %1, %2" : "=v"(pk.x) : "v"(cv[2*j].x),   "v"(cv[2*j].y));
            asm("v_cvt_pk_bf16_f32 %0, %1, %2" : "=v"(pk.y) : "v"(cv[2*j].z),   "v"(cv[2*j].w));
            asm("v_cvt_pk_bf16_f32 %0, %1, %2" : "=v"(pk.z) : "v"(cv[2*j+1].x), "v"(cv[2*j+1].y));
            asm("v_cvt_pk_bf16_f32 %0, %1, %2" : "=v"(pk.w) : "v"(cv[2*j+1].z), "v"(cv[2*j+1].w));
            const int dch = cseg * 4 + j;                 // 16B chunk idx 0..63
            *(uint4*)(smem + OFF_CLDS + ck * 1024 + ((dch ^ (ck & 7)) << 4)) = pk;
        }
        c2p += __shfl_xor(c2p, 1); c2p += __shfl_xor(c2p, 2);
        c2p += __shfl_xor(c2p, 4); c2p += __shfl_xor(c2p, 8);
        if ((l & 15) == 0) c2_l[ck] = c2p;
        if (t < KK) { float sc = scale[t]; s2_l[t] = sc * sc; }
    }

    f32x4 accB[8];
#pragma unroll
    for (int dt = 0; dt < 8; ++dt) accB[dt] = (f32x4){0.f, 0.f, 0.f, 0.f};
    float asum_acc[8] = {0.f, 0.f, 0.f, 0.f, 0.f, 0.f, 0.f, 0.f};

#pragma unroll
    for (int s = 0; s < SUBT; ++s) {
        // ---- convert vaA/vaB -> xbuf (swizzled b64 writes) + x2 partials ----
        {
            float p0 = 0, p1 = 0, p2 = 0, p3 = 0;
#pragma unroll
            for (int j = 0; j < 8; ++j) {
                float4 v = (j < 4) ? vaA[j] : vaB[j - 4];
                uint2 pk;
                asm("v_cvt_pk_bf16_f32 %0, %1, %2" : "=v"(pk.x) : "v"(v.x), "v"(v.y));
                asm("v_cvt_pk_bf16_f32 %0, %1, %2" : "=v"(pk.y) : "v"(v.z), "v"(v.w));
                const int r = w * 64 + j * 8 + lr;
                *(uint2*)(smem + OFF_XBUF + r * 80 + wswz) = pk;
                p0 += v.x * v.x; p1 += v.y * v.y;
                p2 += v.z * v.z; p3 += v.w * v.w;
            }
            p0 += __shfl_xor(p0, 8); p0 += __shfl_xor(p0, 16); p0 += __shfl_xor(p0, 32);
            p1 += __shfl_xor(p1, 8); p1 += __shfl_xor(p1, 16); p1 += __shfl_xor(p1, 32);
            p2 += __shfl_xor(p2, 8); p2 += __shfl_xor(p2, 16); p2 += __shfl_xor(p2, 32);
            p3 += __shfl_xor(p3, 8); p3 += __shfl_xor(p3, 16); p3 += __shfl_xor(p3, 32);
            if (lr == 0) {
                float4 p4 = {p0, p1, p2, p3};
                *(float4*)((char*)smem + OFF_X2P + w * 128 + lc * 16) = p4;
            }
        }
        SYNCL();   // 1: xbuf + x2_part visible (also gates c_lds/c2/s2 at s=0)

        // ---- issue next subtile's first-half loads (all waves, early) ----
        if (s < SUBT - 1) {
#pragma unroll
            for (int j = 0; j < 4; ++j)
                vaA[j] = *(const float4*)(xrow + (size_t)(j * 8) * NN + (s + 1) * TNS);
        }

        // ---- phase A + softmax fused (waves 0-1, boosted priority) ----
        if (w < 2) {
            __builtin_amdgcn_s_setprio(1);
            f32x4 accA0 = {0.f, 0.f, 0.f, 0.f}, accA1 = {0.f, 0.f, 0.f, 0.f};
            const int nloc = w * 16 + li;
            const int nc = nloc >> 3, nr = nloc & 7;
            for (int ch = 0; ch < 16; ++ch) {
                const int dbase = ch * 32 + g * 8;
                short8v bf;
#pragma unroll
                for (int j = 0; j < 8; ++j) {
                    const int d = dbase + j;
                    bf[j] = (short)xbuf[d * ROWX + ((nc ^ (d & 3)) << 3) + nr];
                }
                const int csw = ((ch * 4 + g) ^ (li & 7)) << 3;
                short8v a0 = *(const short8v*)(c_lds + li * DD + csw);
                short8v a1 = *(const short8v*)(c_lds + (16 + li) * DD + csw);
                accA0 = __builtin_amdgcn_mfma_f32_16x16x32_bf16(a0, bf, accA0, 0, 0, 0);
                accA1 = __builtin_amdgcn_mfma_f32_16x16x32_bf16(a1, bf, accA1, 0, 0, 0);
            }
            // softmax over k for column nloc
            float x2v = 0.f;
#pragma unroll
            for (int p = 0; p < 8; ++p) x2v += x2_part[p * 32 + nloc];
            float sl[8];
            float mx = -3.4e38f;
#pragma unroll
            for (int r = 0; r < 4; ++r) {
                float v0 = s2_l[4 * g + r]      * (x2v - 2.f * accA0[r] + c2_l[4 * g + r]);
                float v1 = s2_l[16 + 4 * g + r] * (x2v - 2.f * accA1[r] + c2_l[16 + 4 * g + r]);
                sl[r] = v0; sl[4 + r] = v1;
                mx = fmaxf(mx, fmaxf(v0, v1));
            }
            mx = fmaxf(mx, __shfl_xor(mx, 16));
            mx = fmaxf(mx, __shfl_xor(mx, 32));
            float sum = 0.f;
#pragma unroll
            for (int i = 0; i < 8; ++i) { sl[i] = __expf(sl[i] - mx); sum += sl[i]; }
            sum += __shfl_xor(sum, 16);
            sum += __shfl_xor(sum, 32);
            const float inv = 1.f / sum;
#pragma unroll
            for (int i = 0; i < 8; ++i) {
                float a = sl[i] * inv;
                int k = (i < 4) ? (4 * g + i) : (16 + 4 * g + (i - 4));
                a_t[k * ROWA + nloc] = (u16)f2bf(a);
                float ssum = a;
                ssum += __shfl_xor(ssum, 1); ssum += __shfl_xor(ssum, 2);
                ssum += __shfl_xor(ssum, 4); ssum += __shfl_xor(ssum, 8);
                asum_acc[i] += ssum;    // valid on li==0
            }
            __builtin_amdgcn_s_setprio(0);
        }

        // ---- issue next subtile's second-half loads ----
        // waves 2-7 reach this right after vaA issue (they skip phase A);
        // waves 0-1 issue after their A+SM work -> staggered chip-level demand
        if (s < SUBT - 1) {
#pragma unroll
            for (int j = 0; j < 4; ++j)
                vaB[j] = *(const float4*)(xrow + (size_t)((j + 4) * 8) * NN + (s + 1) * TNS);
        }
        SYNCL();   // 2: a_t ready

        // ---- phase B (all 8 waves): e[k-tile][128 d per wave] += a . x^T ----
        {
            const int kt = w >> 2, dblk = w & 3;
            short8v af = *(const short8v*)(a_t + (kt * 16 + li) * ROWA + g * 8);
#pragma unroll
            for (int dt = 0; dt < 8; ++dt) {
                const int d = dblk * 128 + dt * 16 + li;
                short8v xf = *(const short8v*)(xbuf + d * ROWX + ((g ^ (d & 3)) << 3));
                accB[dt] = __builtin_amdgcn_mfma_f32_16x16x32_bf16(af, xf, accB[dt], 0, 0, 0);
            }
        }
        SYNCL();   // 3: xbuf free for next convert
    }

    // ---- asum -> ws ----
    if (w < 2 && li == 0) {
#pragma unroll
        for (int i = 0; i < 8; ++i) {
            int k = (i < 4) ? (4 * g + i) : (16 + 4 * g + (i - 4));
            asum_p[w * KK + k] = asum_acc[i];
        }
    }
    __syncthreads();
    if (t < KK) ws_asum[(size_t)blk * KK + t] = asum_p[t] + asum_p[KK + t];

    // ---- e partials -> ws (once per block) ----
    {
        const int kt = w >> 2, dblk = w & 3;
        const size_t ebase = (size_t)blk * KK * DD;
#pragma unroll
        for (int dt = 0; dt < 8; ++dt)
#pragma unroll
            for (int r = 0; r < 4; ++r) {
                int k = kt * 16 + 4 * g + r;
                int d = dblk * 128 + dt * 16 + li;
                ws_e[ebase + (size_t)k * DD + d] = (PART)(accB[dt][r]);
            }
    }
}

// ---------------- K2: reduce 32 partials, subtract asum*c ----------------
__global__ void k2_reduce_h(const __half2* __restrict__ ws_e, const float* __restrict__ ws_asum,
                            const float* __restrict__ cw, float* __restrict__ out) {
    int tid = blockIdx.x * blockDim.x + threadIdx.x;   // 131072
    int d2 = tid & 255;
    int k = (tid >> 8) & (KK - 1);
    int b = tid >> 13;
    const __half2* pe = ws_e + ((size_t)(b * NGRP) * KK + k) * 256 + d2;
    const float* pa = ws_asum + b * NGRP * KK + k;
    float s0 = 0.f, s1 = 0.f, as = 0.f;
#pragma unroll
    for (int tl = 0; tl < NGRP; ++tl) {
        float2 f = __half22float2(pe[(size_t)tl * KK * 256]);
        s0 += f.x; s1 += f.y;
        as += pa[tl * KK];
    }
    int d = d2 * 2;
    float c0 = cw[k * DD + d], c1 = cw[k * DD + d + 1];
    float2 o; o.x = s0 - as * c0; o.y = s1 - as * c1;
    *(float2*)(out + ((size_t)(b * KK + k) * DD + d)) = o;
}

__global__ void k2_reduce_f(const float* __restrict__ ws_e, const float* __restrict__ ws_asum,
                            const float* __restrict__ cw, float* __restrict__ out) {
    int tid = blockIdx.x * blockDim.x + threadIdx.x;   // 262144
    int d = tid & (DD - 1);
    int k = (tid >> 9) & (KK - 1);
    int b = tid >> 14;
    float s = 0.f, as = 0.f;
#pragma unroll
    for (int tl = 0; tl < NGRP; ++tl) {
        int blk = b * NGRP + tl;
        s += ws_e[((size_t)blk * KK + k) * DD + d];
        as += ws_asum[(size_t)blk * KK + k];
    }
    out[tid] = s - as * cw[k * DD + d];
}

extern "C" void kernel_launch(void* const* d_in, const int* in_sizes, int n_in,
                              void* d_out, int out_size, void* d_ws, size_t ws_size,
                              hipStream_t stream) {
    const float* x = (const float*)d_in[0];
    const float* cw = (const float*)d_in[1];
    const float* scale = (const float*)d_in[2];
    float* out = (float*)d_out;

    char* ws = (char*)d_ws;
    float* ws_asum = (float*)ws;                // 512*32*4 = 65536 B
    char*  e_ptr   = ws + 65536;

    const size_t need_h = 65536 + (size_t)NBLK * KK * DD * sizeof(__half);

    if (ws_size >= need_h) {
        k1_fused<__half><<<NBLK, 512, LDS_TOTAL, stream>>>(x, cw, scale, ws_asum, (__half*)e_ptr);
        k2_reduce_h<<<(BB * KK * 256) / 256, 256, 0, stream>>>((const __half2*)e_ptr, ws_asum, cw, out);
    } else {
        k1_fused<float><<<NBLK, 512, LDS_TOTAL, stream>>>(x, cw, scale, ws_asum, (float*)e_ptr);
        k2_reduce_f<<<(BB * KK * DD) / 256, 256, 0, stream>>>((const float*)e_ptr, ws_asum, cw, out);
    }
}